// Round 3
// baseline (202.869 us; speedup 1.0000x reference)
//
#include <hip/hip_runtime.h>

// Multi-head causal attention fwd, B=2 S=2048 D=1024 H=16 DK=DV=64.
// fp32 I/O; internal bf16 MFMA pipeline.
// 4 dispatches: convert, fused-QKV gemm, flash-attn, final gemm.
// v9: attn restructured for balance + conflict-free LDS + pipelining:
//  - causal pairing: each block owns q-tiles (p, 31-p) -> 17 compute-tiles
//    per block, 512 identical blocks (2/CU), no straggler tail;
//  - both q-tiles consume the SAME staged K/V tile (frags read once,
//    used twice) -> ~30% less LDS traffic;
//  - XOR bank swizzle on K/V tiles (applied to global_load_lds SOURCE,
//    LDS dest linear; read with same XOR) -> conflict-free ds_read_b128;
//  - 2-phase LDS double buffer, one barrier/tile, staging hidden under
//    compute; XCD-chunked work mapping (8 bh per XCD fits 4MiB L2).

typedef __bf16 bf16;
typedef __bf16 bf16x4 __attribute__((ext_vector_type(4)));
typedef __bf16 bf16x8 __attribute__((ext_vector_type(8)));
typedef float  f32x4  __attribute__((ext_vector_type(4)));

#define B_  2
#define S_  2048
#define D_  1024
#define H_  16
#define HD  64
#define NEG_BIG (-3.0e38f)
#define SCALE_LOG2E 0.1803368801111204f   // (1/8) * log2(e)

__device__ __forceinline__ void lds16(const void* g, void* l) {
    __builtin_amdgcn_global_load_lds((const __attribute__((address_space(1))) void*)g,
                                     (__attribute__((address_space(3))) void*)l, 16, 0, 0);
}

__device__ __forceinline__ f32x4 mfma16(bf16x8 a, bf16x8 b, f32x4 c) {
    return __builtin_amdgcn_mfma_f32_16x16x32_bf16(a, b, c, 0, 0, 0);
}

// ---------------- fp32 -> bf16 convert pre-pass ----------------
__global__ __launch_bounds__(256) void convert_k(const float* __restrict__ X,
                                                 const float* __restrict__ wq,
                                                 const float* __restrict__ wk,
                                                 const float* __restrict__ wv,
                                                 const float* __restrict__ wo,
                                                 bf16* __restrict__ dst) {
    const int gid = blockIdx.x * 256 + threadIdx.x;
    const int i   = gid * 4;
    const float* src;
    int off;
    if      (i < (4 << 20)) { src = X;  off = 0; }
    else if (i < (5 << 20)) { src = wq; off = 4 << 20; }
    else if (i < (6 << 20)) { src = wk; off = 5 << 20; }
    else if (i < (7 << 20)) { src = wv; off = 6 << 20; }
    else                    { src = wo; off = 7 << 20; }
    const float4 v = *(const float4*)(src + (i - off));
    bf16x4 p;
    p[0] = (bf16)v.x; p[1] = (bf16)v.y; p[2] = (bf16)v.z; p[3] = (bf16)v.w;
    *(bf16x4*)(dst + i) = p;
}

// ---------------- fused QKV GEMM (768 blocks = 3/CU) ----------------
// seg 0: Q = X Wq^T (+bq)*SCALE_LOG2E -> [B,H,S,64]
// seg 1: K = X Wk^T (+bk)             -> [B,H,S,64]
// seg 2: V = X Wv^T (+bv)             -> [B,H,64,S] (bf16x4 along s; L2 merges)
__global__ __launch_bounds__(256) void gemm_qkv(const bf16* __restrict__ A,
                                                const bf16* __restrict__ Wq,
                                                const bf16* __restrict__ Wk,
                                                const bf16* __restrict__ Wv,
                                                const float* __restrict__ bq,
                                                const float* __restrict__ bk,
                                                const float* __restrict__ bv,
                                                bf16* __restrict__ Qw,
                                                bf16* __restrict__ Kw,
                                                bf16* __restrict__ Vw) {
    constexpr int K = 1024;
    __shared__ bf16 sA[128 * 32];
    __shared__ bf16 sB[128 * 32];
    const int tid  = threadIdx.x;
    const int l15  = tid & 15;
    const int quad = (tid & 63) >> 4;
    const int wid  = tid >> 6;
    const int seg  = blockIdx.x >> 3;
    const int bn   = blockIdx.x & 7;
    const int bm   = blockIdx.y;
    const int wm   = (wid >> 1) * 64;
    const int wn   = (wid & 1) * 64;

    const bf16* W    = (seg == 0) ? Wq : (seg == 1) ? Wk : Wv;
    const float* bias = (seg == 0) ? bq : (seg == 1) ? bk : bv;

    const bf16* Ab = A + (size_t)bm * 128 * K;
    const bf16* Wb = W + (size_t)bn * 128 * K;

    f32x4 acc[4][4] = {};

    for (int k0 = 0; k0 < K; k0 += 32) {
        __syncthreads();
        #pragma unroll
        for (int it = 0; it < 2; ++it) {
            int c = it * 256 + tid;
            int row = c >> 2, c8 = c & 3;
            lds16(Ab + row * K + k0 + c8 * 8, (char*)sA + c * 16);
            lds16(Wb + row * K + k0 + c8 * 8, (char*)sB + c * 16);
        }
        __syncthreads();
        bf16x8 af[4], bfr[4];
        #pragma unroll
        for (int i = 0; i < 4; ++i)
            af[i] = *(const bf16x8*)&sA[(wm + i * 16 + l15) * 32 + quad * 8];
        #pragma unroll
        for (int i = 0; i < 4; ++i)
            bfr[i] = *(const bf16x8*)&sB[(wn + i * 16 + l15) * 32 + quad * 8];
        #pragma unroll
        for (int mi = 0; mi < 4; ++mi)
            #pragma unroll
            for (int ni = 0; ni < 4; ++ni)
                acc[mi][ni] = mfma16(af[mi], bfr[ni], acc[mi][ni]);
    }

    #pragma unroll
    for (int ni = 0; ni < 4; ++ni) {
        const int n  = bn * 128 + wn + ni * 16 + l15;
        const float bv_ = bias[n];
        const int h = n >> 6;
        #pragma unroll
        for (int mi = 0; mi < 4; ++mi) {
            const int m0 = bm * 128 + wm + mi * 16 + quad * 4;
            if (seg == 2) {   // V transposed: [B,H,64,S]
                const int dv = n & 63;
                const int b = m0 >> 11, s = m0 & 2047;
                bf16x4 pack;
                #pragma unroll
                for (int r = 0; r < 4; ++r) pack[r] = (bf16)(acc[mi][ni][r] + bv_);
                *(bf16x4*)&Vw[(((size_t)(b * H_ + h) * HD + dv) << 11) + s] = pack;
            } else {          // Q,K: [B,H,S,64]
                bf16* C = (seg == 0) ? Qw : Kw;
                const float qs = (seg == 0) ? SCALE_LOG2E : 1.0f;
                const int dk = n & 63;
                #pragma unroll
                for (int r = 0; r < 4; ++r) {
                    const int m = m0 + r, b = m >> 11, s = m & 2047;
                    C[(((size_t)(b * H_ + h) << 11) + s) * HD + dk] =
                        (bf16)((acc[mi][ni][r] + bv_) * qs);
                }
            }
        }
    }
}

// ---------------- final GEMM: out fp32 = A @ Wo^T + bias (512 blocks) -------
__global__ __launch_bounds__(256) void gemm_fin(const bf16* __restrict__ A,
                                                const bf16* __restrict__ W,
                                                const float* __restrict__ bias,
                                                float* __restrict__ C) {
    constexpr int N = 1024, K = 1024;
    __shared__ bf16 sA[64 * 32];
    __shared__ bf16 sB[128 * 32];
    const int tid  = threadIdx.x;
    const int l15  = tid & 15;
    const int quad = (tid & 63) >> 4;
    const int wid  = tid >> 6;
    const int bm   = blockIdx.x >> 3;
    const int bn   = blockIdx.x & 7;
    const int wm   = (wid & 1) * 32;
    const int wn   = (wid >> 1) * 64;

    const bf16* Ab = A + (size_t)bm * 64 * K;
    const bf16* Wb = W + (size_t)bn * 128 * K;

    f32x4 acc[2][4] = {};

    for (int k0 = 0; k0 < K; k0 += 32) {
        __syncthreads();
        {
            int c = tid, row = c >> 2, c8 = c & 3;
            lds16(Ab + row * K + k0 + c8 * 8, (char*)sA + c * 16);
        }
        #pragma unroll
        for (int it = 0; it < 2; ++it) {
            int c = it * 256 + tid;
            int row = c >> 2, c8 = c & 3;
            lds16(Wb + row * K + k0 + c8 * 8, (char*)sB + c * 16);
        }
        __syncthreads();
        bf16x8 af[2], bfr[4];
        #pragma unroll
        for (int i = 0; i < 2; ++i)
            af[i] = *(const bf16x8*)&sA[(wm + i * 16 + l15) * 32 + quad * 8];
        #pragma unroll
        for (int i = 0; i < 4; ++i)
            bfr[i] = *(const bf16x8*)&sB[(wn + i * 16 + l15) * 32 + quad * 8];
        #pragma unroll
        for (int mi = 0; mi < 2; ++mi)
            #pragma unroll
            for (int ni = 0; ni < 4; ++ni)
                acc[mi][ni] = mfma16(af[mi], bfr[ni], acc[mi][ni]);
    }

    #pragma unroll
    for (int ni = 0; ni < 4; ++ni) {
        const int n  = bn * 128 + wn + ni * 16 + l15;
        const float bv = bias[n];
        #pragma unroll
        for (int mi = 0; mi < 2; ++mi) {
            const int m0 = bm * 64 + wm + mi * 16 + quad * 4;
            #pragma unroll
            for (int r = 0; r < 4; ++r)
                C[(size_t)(m0 + r) * N + n] = acc[mi][ni][r] + bv;
        }
    }
}

// ---------------- Flash attention v9 ----------------
// 512 blocks, 256 threads (4 waves), 64 KiB LDS (2 blocks/CU exactly).
// Block p handles q-tiles qtA=p and qtB=31-p (17 compute-tiles each block).
// Both q-tiles consume the same staged K/V tile; K/V frags read once, used
// for both QK^T passes. S^T = K Q^T permuted-row trick (P^T packs
// lane-locally); l rides the MFMA pipe; epilogue LDS-free.
// XOR swizzle: chunk ^= (row>>1&1)|(row>>3&1)<<1 on staging SOURCE + reads.
__global__ __launch_bounds__(256, 2) void attn_k(const bf16* __restrict__ Q,
                                                 const bf16* __restrict__ K,
                                                 const bf16* __restrict__ Vt,
                                                 const float* __restrict__ pmask,
                                                 bf16* __restrict__ Aout) {
    __shared__ bf16 sK[2][2 * 128 * 32];   // [buf][kk][row][32]  16K each
    __shared__ bf16 sV[2][4 * 64 * 32];    // [buf][kc][dv][32]   16K each
    const int tid  = threadIdx.x;
    const int l15  = tid & 15;
    const int quad = (tid & 63) >> 4;
    const int wid  = tid >> 6;           // 0..3 -> q quarter
    // XCD-chunked mapping: XCD x gets work ids [x*64, x*64+64) = 8 bh values
    const int v    = ((blockIdx.x & 7) << 6) | (blockIdx.x >> 3);
    const int bh   = v >> 4;             // 0..31
    const int p    = v & 15;             // 0..15
    const int b    = bh >> 4;
    const int h    = bh & 15;
    const int qtA  = p, qtB = 31 - p;
    const int nktA = (qtA >> 1) + 1;     // 1..8
    const int nktB = (qtB >> 1) + 1;     // 9..16  (always > nktA)

    const bf16* Qg = Q  + (size_t)bh * S_ * HD;
    const bf16* Kg = K  + (size_t)bh * S_ * HD;
    const bf16* Vg = Vt + (size_t)bh * HD * S_;

    // Q B-frags for both q-tiles: n=q=l15, k=kk*32+quad*8+jj
    bf16x8 qbA[2], qbB[2];
    #pragma unroll
    for (int kk = 0; kk < 2; ++kk) {
        qbA[kk] = *(const bf16x8*)&Qg[(qtA * 64 + wid * 16 + l15) * HD + kk * 32 + quad * 8];
        qbB[kk] = *(const bf16x8*)&Qg[(qtB * 64 + wid * 16 + l15) * HD + kk * 32 + quad * 8];
    }

    // permuted K row: lane l15 of frag f holds key (l15>>2)*8 + f*4 + (l15&3)
    const int krow0 = (l15 >> 2) * 8 + (l15 & 3);
    const int qgA   = qtA * 64 + wid * 16 + l15;
    const int qgB   = qtB * 64 + wid * 16 + l15;
    // swizzled chunk offsets (elements): K rows vary in bits {0,1(l15),2(f),3,4(l15>>2)}
    const int ckx = (quad ^ (((l15 >> 1) & 1) | (((l15 >> 2) & 1) << 1))) * 8;
    const int cvx = (quad ^ (((l15 >> 1) & 1) | (((l15 >> 3) & 1) << 1))) * 8;

    bf16x8 onesv;
    #pragma unroll
    for (int i = 0; i < 8; ++i) onesv[i] = (bf16)1.0f;

    f32x4 oA[4] = {}, oB[4] = {};        // O^T: rows dv=dvf*16+quad*4+r, col q=l15
    f32x4 lA = {}, lB = {};              // l[q], replicated across regs

#define STAGE(KT, BUF) do {                                                     \
    _Pragma("unroll")                                                           \
    for (int it = 0; it < 4; ++it) {                                            \
        int c = it * 256 + tid;                                                 \
        { int pl = c >> 9, row = (c >> 2) & 127, c8 = c & 3;                    \
          int sw = c8 ^ (((row >> 1) & 1) | (((row >> 3) & 1) << 1));           \
          lds16(Kg + ((size_t)(KT) * 128 + row) * HD + pl * 32 + sw * 8,        \
                (char*)sK[BUF] + c * 16); }                                     \
        { int kc = c >> 8, dv = (c >> 2) & 63, c8 = c & 3;                      \
          int sw = c8 ^ (((dv >> 1) & 1) | (((dv >> 3) & 1) << 1));             \
          lds16(Vg + (size_t)(KT) * 128 + (size_t)dv * S_ + kc * 32 + sw * 8,   \
                (char*)sV[BUF] + c * 16); }                                     \
    } } while (0)

    // softmax pack: mask + causal + exp2 -> P^T B-frag (lane-local)
    auto softpack = [&](const f32x4* s2, const float4& m0, const float4& m1,
                        bool lastt, int qg, int keyb) -> bf16x8 {
        bf16x8 pb;
        #pragma unroll
        for (int f = 0; f < 2; ++f) {
            const float* mm = f ? (const float*)&m1 : (const float*)&m0;
            #pragma unroll
            for (int r = 0; r < 4; ++r) {
                float vv = fmaf(mm[r], NEG_BIG, s2[f][r]);
                if (lastt && (keyb + f * 4 + r > qg)) vv = NEG_BIG;
                pb[f * 4 + r] = (bf16)exp2f(vv);
            }
        }
        return pb;
    };

    STAGE(0, 0);
    __syncthreads();                     // drain prologue staging
    int cur = 0;
    for (int kt = 0; kt < nktB; ++kt) {
        if (kt + 1 < nktB) STAGE(kt + 1, cur ^ 1);   // issue next-tile loads
        const bool doA   = (kt < nktA);
        const bool lastA = (kt == nktA - 1);
        const bool lastB = (kt == nktB - 1);
        #pragma unroll
        for (int g = 0; g < 4; ++g) {
            // K frags (shared by both q-tiles)
            bf16x8 ka[2][2];
            #pragma unroll
            for (int f = 0; f < 2; ++f)
                #pragma unroll
                for (int kk = 0; kk < 2; ++kk)
                    ka[f][kk] = *(const bf16x8*)
                        &sK[cur][(kk * 128 + g * 32 + krow0 + f * 4) * 32 + ckx];
            // pmask for this 32-key group (per-lane 8 keys)
            const int keyb0 = kt * 128 + g * 32 + quad * 8;
            const float4 pm0 = *(const float4*)&pmask[b * S_ + keyb0];
            const float4 pm1 = *(const float4*)&pmask[b * S_ + keyb0 + 4];
            // S^T for both q-tiles
            f32x4 sB2[2] = {}, sA2[2] = {};
            #pragma unroll
            for (int f = 0; f < 2; ++f)
                #pragma unroll
                for (int kk = 0; kk < 2; ++kk)
                    sB2[f] = mfma16(ka[f][kk], qbB[kk], sB2[f]);
            if (doA) {
                #pragma unroll
                for (int f = 0; f < 2; ++f)
                    #pragma unroll
                    for (int kk = 0; kk < 2; ++kk)
                        sA2[f] = mfma16(ka[f][kk], qbA[kk], sA2[f]);
            }
            // V frags (shared)
            bf16x8 va[4];
            #pragma unroll
            for (int dvf = 0; dvf < 4; ++dvf)
                va[dvf] = *(const bf16x8*)
                    &sV[cur][(g * 64 + dvf * 16 + l15) * 32 + cvx];
            // pass B
            {
                bf16x8 pb = softpack(sB2, pm0, pm1, lastB, qgB, keyb0);
                lB = mfma16(onesv, pb, lB);
                #pragma unroll
                for (int dvf = 0; dvf < 4; ++dvf)
                    oB[dvf] = mfma16(va[dvf], pb, oB[dvf]);
            }
            // pass A (shares ka/va)
            if (doA) {
                bf16x8 pb = softpack(sA2, pm0, pm1, lastA, qgA, keyb0);
                lA = mfma16(onesv, pb, lA);
                #pragma unroll
                for (int dvf = 0; dvf < 4; ++dvf)
                    oA[dvf] = mfma16(va[dvf], pb, oA[dvf]);
            }
        }
        __syncthreads();                 // drains next-tile staging (vmcnt 0)
        cur ^= 1;
    }
#undef STAGE

    // epilogue: fully lane-local; lane holds O[q][dv=dvf*16+quad*4+r], l[q]
    {
        const float inv = 1.f / lA[0];
        const size_t base = ((size_t)b * S_ + qgA) * D_ + h * HD + quad * 4;
        #pragma unroll
        for (int dvf = 0; dvf < 4; ++dvf) {
            bf16x4 pk;
            #pragma unroll
            for (int r = 0; r < 4; ++r) pk[r] = (bf16)(oA[dvf][r] * inv);
            *(bf16x4*)&Aout[base + dvf * 16] = pk;
        }
    }
    {
        const float inv = 1.f / lB[0];
        const size_t base = ((size_t)b * S_ + qgB) * D_ + h * HD + quad * 4;
        #pragma unroll
        for (int dvf = 0; dvf < 4; ++dvf) {
            bf16x4 pk;
            #pragma unroll
            for (int r = 0; r < 4; ++r) pk[r] = (bf16)(oB[dvf][r] * inv);
            *(bf16x4*)&Aout[base + dvf * 16] = pk;
        }
    }
}

extern "C" void kernel_launch(void* const* d_in, const int* in_sizes, int n_in,
                              void* d_out, int out_size, void* d_ws, size_t ws_size,
                              hipStream_t stream) {
    const float* X   = (const float*)d_in[0];
    const float* pm  = (const float*)d_in[1];
    const float* wq  = (const float*)d_in[2];
    const float* bq  = (const float*)d_in[3];
    const float* wk  = (const float*)d_in[4];
    const float* bk  = (const float*)d_in[5];
    const float* wv  = (const float*)d_in[6];
    const float* bvb = (const float*)d_in[7];
    const float* wo  = (const float*)d_in[8];
    const float* bo  = (const float*)d_in[9];
    float* out = (float*)d_out;

    char* ws = (char*)d_ws;
    bf16* Xb  = (bf16*)(ws);                  // 4M elems  8 MiB
    bf16* Wqb = (bf16*)(ws + (8u  << 20));    // 1M elems  2 MiB each
    bf16* Wkb = (bf16*)(ws + (10u << 20));
    bf16* Wvb = (bf16*)(ws + (12u << 20));
    bf16* Wob = (bf16*)(ws + (14u << 20));
    bf16* Qw  = (bf16*)(ws + (16u << 20));    // [B,H,S,64]  8 MiB
    bf16* Kw  = (bf16*)(ws + (24u << 20));    // [B,H,S,64]  8 MiB
    bf16* Vw  = (bf16*)(ws + (32u << 20));    // [B,H,64,S]  8 MiB
    bf16* Aw  = (bf16*)(ws + (40u << 20));    // [B*S, 1024] 8 MiB

    convert_k<<<dim3(8192), dim3(256), 0, stream>>>(X, wq, wk, wv, wo, Xb);
    gemm_qkv<<<dim3(24, 32), dim3(256), 0, stream>>>(Xb, Wqb, Wkb, Wvb,
                                                     bq, bk, bvb, Qw, Kw, Vw);
    attn_k<<<dim3(512), dim3(256), 0, stream>>>(Qw, Kw, Vw, pm, Aw);
    gemm_fin<<<dim3(512), dim3(256), 0, stream>>>(Aw, Wob, bo, out);
}